// Round 2
// baseline (460.949 us; speedup 1.0000x reference)
//
#include <hip/hip_runtime.h>

// B=16 E=128 W=256 HID=64 HOR=12
// row = b*128+e (2048 rows); in row-parallel kernels: one 64-lane wave per row.
// Multi-launch design: kernel boundaries serve as grid barriers (no cooperative
// launch, no co-residency assumption). 16 launches total.

struct Params {
  const float *__restrict__ x, *__restrict__ noise, *__restrict__ aw, *__restrict__ ab,
              *__restrict__ pe_w1, *__restrict__ pe_b1, *__restrict__ bn_g, *__restrict__ bn_b,
              *__restrict__ bn_m, *__restrict__ bn_v, *__restrict__ pe_w2, *__restrict__ pe_b2,
              *__restrict__ w1, *__restrict__ b1, *__restrict__ w2, *__restrict__ b2,
              *__restrict__ w3, *__restrict__ b3, *__restrict__ wl, *__restrict__ bl,
              *__restrict__ wr, *__restrict__ br, *__restrict__ attn, *__restrict__ out_w,
              *__restrict__ out_b, *__restrict__ ce_w, *__restrict__ ce_b, *__restrict__ cd_w,
              *__restrict__ cd_b, *__restrict__ q_w, *__restrict__ q_b, *__restrict__ k_w,
              *__restrict__ k_b;
  float* ws;
  float* out;
};

__device__ __forceinline__ float fast_tanh(float x) {
  float t = exp2f(fminf(2.8853900818f * x, 126.0f));   // exp(2x)
  return 1.0f - 2.0f * __builtin_amdgcn_rcpf(t + 1.0f);
}
__device__ __forceinline__ float fast_sigmoid(float x) {
  float t = exp2f(fminf(-1.44269504f * x, 126.0f));
  return __builtin_amdgcn_rcpf(1.0f + t);
}
__device__ __forceinline__ float wsum(float v) {
  #pragma unroll
  for (int m = 1; m < 64; m <<= 1) v += __shfl_xor(v, m, 64);
  return v;
}
__device__ __forceinline__ float wmax(float v) {
  #pragma unroll
  for (int m = 1; m < 64; m <<= 1) v = fmaxf(v, __shfl_xor(v, m, 64));
  return v;
}

// workspace layout (float offsets). total 1990688 floats ~= 7.97 MB
#define OFF_MS   0        // mean[16], std[16]
#define OFF_Q    32       // 2 x 2048 x 4 (double-buffered Q)
#define OFF_QV   16416    // q: 2048 x 32
#define OFF_KV   81952    // k: 2048 x 32
#define OFF_GL   147488   // gl: 2 x 2048 x 64
#define OFF_GR   409632   // gr: 2 x 2048 x 64
#define OFF_H0   671776   // h0bn: 16 x 32 x 256
#define OFF_XW   802848   // window: 2048 x 272 (cols 0..266 used)
#define OFF_G    1359904  // G: 2048 x 272 (s in [0,264) used)
#define OFF_ADJ  1916960  // adj_bin: 2048 x 128 uint8 (= 65536 floats)
#define OFF_WLT  1982496  // wl transposed [f][o]: 4096
#define OFF_WRT  1986592  // wr transposed [f][o]: 4096

// ---------- K1: per-b mean/std + h0 = bn(relu(conv5(xn))) ----------
// grid 512x256; idx = b*8192 + c*256 + w; all threads of a block share b.
__global__ __launch_bounds__(256)
void k1_h0(Params P) {
  __shared__ float red[8];
  const int tid = threadIdx.x, blk = blockIdx.x;
  const int idx = blk * 256 + tid;
  const int b = idx >> 13, c = (idx >> 8) & 31, w = idx & 255;
  const int lane = tid & 63, wv = tid >> 6;

  float v = P.x[b * 256 + w];              // w == tid here (256 threads/block)
  float s = wsum(v), s2 = wsum(v * v);
  if (lane == 0) { red[wv] = s; red[4 + wv] = s2; }
  __syncthreads();
  float st  = red[0] + red[1] + red[2] + red[3];
  float st2 = red[4] + red[5] + red[6] + red[7];
  float mean = st * (1.f / 256.f);
  float var  = st2 * (1.f / 256.f) - mean * mean;
  float sd   = sqrtf(var);
  float* ms = P.ws + OFF_MS;
  if (tid == 0) { ms[b] = mean; ms[16 + b] = sd; }  // duplicate identical writes OK

  float rstd = 1.f / sd;
  float acc = P.pe_b1[c];
  #pragma unroll
  for (int k = 0; k < 5; k++) {
    int u = w - 2 + k;
    float xv = (u >= 0 && u < 256) ? (P.x[b * 256 + u] - mean) * rstd : 0.f;
    acc += P.pe_w1[c * 5 + k] * xv;
  }
  acc = fmaxf(acc, 0.f);
  float sc = P.bn_g[c] / sqrtf(P.bn_v[c] + 1e-5f);
  (P.ws + OFF_H0)[idx] = (acc - P.bn_m[c]) * sc + P.bn_b[c];
}

// ---------- K2: xf = affine(conv1x1(h0)) -> initial window ----------
// grid 2048x256; idx = b*32768 + e*256 + w
__global__ __launch_bounds__(256)
void k2_xf(Params P) {
  const int idx = blockIdx.x * 256 + threadIdx.x;
  const int b = idx >> 15, e = (idx >> 8) & 127, w = idx & 255;
  const float* w2p  = P.pe_w2 + e * 32;
  const float* hcol = P.ws + OFF_H0 + b * 8192 + w;
  float acc = P.pe_b2[e];
  #pragma unroll 8
  for (int c = 0; c < 32; c++) acc += w2p[c] * hcol[c * 256];
  acc = acc * P.aw[e] + P.ab[e];
  (P.ws + OFF_XW)[(b * 128 + e) * 272 + w] = acc;
}

// ---------- K3: telescoped CNN precompute G[s] = cnn(x[s..s+3]), s<253 ----------
// grid 512x256; one wave per row, 4 s-iterations of 64 lanes.
__global__ __launch_bounds__(256)
void k3_G(Params P) {
  const int tid = threadIdx.x, lane = tid & 63, wv = tid >> 6;
  const int vwg = blockIdx.x * 4 + wv;                    // row
  const int es  = __builtin_amdgcn_readfirstlane(vwg) & 127;
  const float* w1p = P.w1 + es * 128;
  const float* w2p = P.w2 + es * 512;
  const float* w3p = P.w3 + es * 64;
  const float* b1p = P.b1 + es * 64;
  const float* b2p = P.b2 + es * 64;
  const float  b3v = P.b3[es];
  const float* xr  = P.ws + OFF_XW + vwg * 272;
  float* Gr = P.ws + OFF_G + vwg * 272;
  #pragma unroll 1
  for (int it = 0; it < 4; it++) {
    int s = lane + 64 * it;
    bool ok = (s < 253);
    float X0 = 0.f, X1 = 0.f, X2 = 0.f, X3 = 0.f;
    if (ok) { X0 = xr[s]; X1 = xr[s + 1]; X2 = xr[s + 2]; X3 = xr[s + 3]; }
    float acc = 0.f;
    #pragma unroll 1
    for (int g2 = 0; g2 < 16; g2++) {
      float h1v[8];
      #pragma unroll
      for (int ic = 0; ic < 4; ic++) {
        int ch = g2 * 4 + ic;
        float ww0 = w1p[ch * 2], ww1 = w1p[ch * 2 + 1], bb = b1p[ch];
        h1v[ic * 2 + 0] = fast_tanh(bb + ww0 * X0 + ww1 * X1);
        h1v[ic * 2 + 1] = fast_tanh(bb + ww0 * X2 + ww1 * X3);
      }
      #pragma unroll
      for (int oc = 0; oc < 4; oc++) {
        int ch = g2 * 4 + oc;
        const float* wq = w2p + ch * 8;
        float a2 = b2p[ch];
        #pragma unroll
        for (int u = 0; u < 8; u++) a2 += wq[u] * h1v[u];
        acc += w3p[ch] * fast_tanh(a2);
      }
    }
    if (ok) Gr[s] = fast_tanh(b3v + acc);
  }
}

// ---------- K4: q,k projections + Wl/Wr transpose staging ----------
// grid 512x256; gtid in [0,131072): half 0 -> q, half 1 -> k
__global__ __launch_bounds__(256)
void k4_qk(Params P) {
  const int gtid = blockIdx.x * 256 + threadIdx.x;
  if (gtid < 4096) {
    int o = gtid >> 6, f = gtid & 63;
    (P.ws + OFF_WLT)[f * 64 + o] = P.wl[gtid];
  } else if (gtid < 8192) {
    int i = gtid - 4096;
    int o = i >> 6, f = i & 63;
    (P.ws + OFF_WRT)[f * 64 + o] = P.wr[i];
  }
  const int half = gtid >> 16;
  const int idx  = gtid & 65535;          // row*32 + h
  const int row  = idx >> 5, h = idx & 31;
  const float* wm  = half ? P.k_w : P.q_w;
  const float* bv  = half ? P.k_b : P.q_b;
  const float* xr  = P.ws + OFF_XW + row * 272;
  const float* wrw = wm + h * 256;
  float acc = bv[h];
  #pragma unroll 8
  for (int w = 0; w < 256; w += 4) {
    float4 xx = *(const float4*)(xr + w);
    float4 wq = *(const float4*)(wrw + w);
    acc += xx.x * wq.x + xx.y * wq.y + xx.z * wq.z + xx.w * wq.w;
  }
  ((half ? P.ws + OFF_KV : P.ws + OFF_QV))[idx] = acc;
}

// ---------- K5: adjacency softmax+binarize, Q0, gl/gr for t=0 ----------
// grid 512x256; one wave per row.
__global__ __launch_bounds__(256)
void k5_adj(Params P) {
  __shared__ float hbuf[4 * 64];
  const int tid = threadIdx.x, lane = tid & 63, wv = tid >> 6;
  const int row = blockIdx.x * 4 + wv;
  const int b = row >> 7;
  float* ws = P.ws;
  float* hb = hbuf + wv * 64;
  unsigned char* adjb = (unsigned char*)(ws + OFF_ADJ);

  if (lane < 32) hb[lane] = (ws + OFF_QV)[row * 32 + lane];
  __syncthreads();
  float ev0, ev1;
  #pragma unroll
  for (int half = 0; half < 2; half++) {
    int j = lane + half * 64;
    const float* kr = ws + OFF_KV + (b * 128 + j) * 32;
    float acc = 0.f;
    #pragma unroll
    for (int h = 0; h < 32; h += 4) {
      float4 kk = *(const float4*)(kr + h);
      float4 qq = *(const float4*)(hb + h);
      acc += qq.x * kk.x + qq.y * kk.y + qq.z * kk.z + qq.w * kk.w;
    }
    if (half == 0) ev0 = acc; else ev1 = acc;
  }
  float m   = wmax(fmaxf(ev0, ev1));
  float p0  = __expf(ev0 - m), p1 = __expf(ev1 - m);
  float inv = 1.f / wsum(p0 + p1);
  float a0 = p0 * inv, a1 = p1 * inv;
  P.out[38912 + row * 128 + lane]      = a0;
  P.out[38912 + row * 128 + lane + 64] = a1;
  adjb[row * 128 + lane]      = (a0 > 0.5f) ? 1 : 0;
  adjb[row * 128 + lane + 64] = (a1 > 0.5f) ? 1 : 0;
  float* Qb = ws + OFF_Q;
  if (lane == 0) { Qb[row * 4] = 1.f; Qb[row * 4 + 1] = 0.f; Qb[row * 4 + 2] = 0.f; }
  __syncthreads();
  hb[lane] = (ws + OFF_G)[row * 272 + 4 * lane];   // h(0)[lane]
  __syncthreads();
  const float* WlT = ws + OFF_WLT;
  const float* WrT = ws + OFF_WRT;
  float glx = P.bl[lane], grx = P.br[lane];
  #pragma unroll 4
  for (int f = 0; f < 64; f++) {
    float hv = hb[f];
    glx += hv * WlT[f * 64 + lane];
    grx += hv * WrT[f * 64 + lane];
  }
  (ws + OFF_GL)[row * 64 + lane] = glx;
  (ws + OFF_GR)[row * 64 + lane] = grx;
}

// ---------- K6..K17: one scan step (t passed as arg) ----------
// grid 512x256; one wave per row. Kernel boundary = grid barrier.
__global__ __launch_bounds__(256)
void k_step(Params P, int t) {
  __shared__ float wscb[4 * 320];   // per wave: h1buf 128 | abuf 128 | hbuf 64
  __shared__ float attnS[64];
  const int tid = threadIdx.x, lane = tid & 63, wv = tid >> 6;
  const int row = blockIdx.x * 4 + wv;
  const int b = row >> 7, e = row & 127;
  float* ws = P.ws;
  float* h1b  = wscb + wv * 320;
  float* abuf = wscb + wv * 320 + 128;
  float* hb   = wscb + wv * 320 + 256;
  const unsigned char* arow = (const unsigned char*)(ws + OFF_ADJ) + row * 128;
  const float* grow_G = ws + OFF_G + row * 272;
  float* xwr = ws + OFF_XW + row * 272;
  const float* WlT = ws + OFF_WLT;
  const float* WrT = ws + OFF_WRT;

  if (tid < 64) attnS[tid] = P.attn[tid];

  // per-row invariants
  float cew0 = P.ce_w[lane * 3], cew1 = P.ce_w[lane * 3 + 1], cew2 = P.ce_w[lane * 3 + 2];
  float cebv = P.ce_b[lane];
  float cdw0 = P.cd_w[lane], cdw1 = P.cd_w[64 + lane], cdw2 = P.cd_w[128 + lane], cdw3 = P.cd_w[192 + lane];
  float cdb0 = P.cd_b[0], cdb1 = P.cd_b[1], cdb2 = P.cd_b[2], cdb3 = P.cd_b[3];
  float outw = P.out_w[e * 64 + lane], outb = P.out_b[e];
  float blv = P.bl[lane], brv = P.br[lane];

  const float* glp  = ws + OFF_GL + (t & 1) * 131072 + b * 8192;
  const float* grp  = ws + OFF_GR + (t & 1) * 131072 + b * 8192;
  const float* Qold = ws + OFF_Q + (t & 1) * 8192;
  float*       Qnew = ws + OFF_Q + ((t + 1) & 1) * 8192;

  float h_own = grow_G[t + 4 * lane];
  float gri   = grp[e * 64 + lane];
  hb[lane] = gri;
  __syncthreads();

  // GAT logits over j, mask, softmax
  float ev0, ev1;
  #pragma unroll
  for (int half = 0; half < 2; half++) {
    int j = lane + half * 64;
    const float* glr = glp + j * 64;
    float acc = 0.f;
    #pragma unroll
    for (int f = 0; f < 64; f += 4) {
      float4 g4 = *(const float4*)(glr + f);
      float4 hq = *(const float4*)(hb + f);
      float4 aq = *(const float4*)(attnS + f);
      float v;
      v = hq.x + g4.x; acc += fmaxf(v, 0.2f * v) * aq.x;
      v = hq.y + g4.y; acc += fmaxf(v, 0.2f * v) * aq.y;
      v = hq.z + g4.z; acc += fmaxf(v, 0.2f * v) * aq.z;
      v = hq.w + g4.w; acc += fmaxf(v, 0.2f * v) * aq.w;
    }
    float evv = arow[j] ? acc : -1e20f;
    if (half == 0) ev0 = evv; else ev1 = evv;
  }
  float m   = wmax(fmaxf(ev0, ev1));
  float p0  = __expf(ev0 - m), p1 = __expf(ev1 - m);
  float inv = 1.f / wsum(p0 + p1);
  abuf[lane]      = p0 * inv;
  abuf[lane + 64] = p1 * inv;
  __syncthreads();

  // h_temp[f=lane] = sum_j a[j] * gr[j][f]
  float ht = 0.f;
  #pragma unroll 4
  for (int j0 = 0; j0 < 128; j0 += 4) {
    float4 aq = *(const float4*)(abuf + j0);
    ht += aq.x * grp[(j0 + 0) * 64 + lane];
    ht += aq.y * grp[(j0 + 1) * 64 + lane];
    ht += aq.z * grp[(j0 + 2) * 64 + lane];
    ht += aq.w * grp[(j0 + 3) * 64 + lane];
  }

  float q0 = Qold[row * 4], q1 = Qold[row * 4 + 1], q2 = Qold[row * 4 + 2];
  float hc = fast_tanh(cebv + q0 * cew0 + q1 * cew1 + q2 * cew2);
  float hf = h_own + fast_tanh(ht) + hc;

  float xp = wsum(hf * outw) + outb;
  float d0 = wsum(hf * cdw0);
  float d1 = wsum(hf * cdw1);
  float d2 = wsum(hf * cdw2);
  float d3 = wsum(hf * cdw3);
  float al = fast_sigmoid(d0 + cdb0);
  float be = fast_sigmoid(d1 + cdb1);
  float ga = fast_sigmoid(d2 + cdb2);
  float et = fast_sigmoid(d3 + cdb3);

  float ec = 0.f;
  if (arow[lane])      ec += Qold[(b * 128 + lane) * 4 + 1];
  if (arow[lane + 64]) ec += Qold[(b * 128 + lane + 64) * 4 + 1];
  ec = wsum(ec);

  float Hn = q0 - al * q0;
  float En = q1 + be * q0 - ga * q1 + 0.1f * ec;
  float Vn = q2 + et * q1 + P.noise[t * 2048 + row] * 0.01f;
  if (lane == 0) {
    Qnew[row * 4]     = Hn;
    Qnew[row * 4 + 1] = En;
    Qnew[row * 4 + 2] = Vn;
    xwr[256 + t] = xp;
    float awv = P.aw[e], abv = P.ab[e];
    float stdb = (ws + OFF_MS)[16 + b], meanb = (ws + OFF_MS)[b];
    P.out[row * 12 + t] = (xp - abv) / awv * stdb + meanb;
    if (t == 11) {
      P.out[24576 + row * 3]     = Hn;
      P.out[24576 + row * 3 + 1] = En;
      P.out[24576 + row * 3 + 2] = Vn;
      P.out[30720 + row * 4]     = al;
      P.out[30720 + row * 4 + 1] = be;
      P.out[30720 + row * 4 + 2] = ga;
      P.out[30720 + row * 4 + 3] = et;
    }
  }

  if (t < 11) {
    // incremental G: one new cnn column, lanes = channels
    int s = 253 + t;
    float X0 = xwr[s];
    float X1 = xwr[s + 1];
    float X2 = xwr[s + 2];
    float X3 = xp;
    float w10 = P.w1[e * 128 + lane * 2], w11 = P.w1[e * 128 + lane * 2 + 1];
    float b1v = P.b1[e * 64 + lane], b2v = P.b2[e * 64 + lane];
    float w3v = P.w3[e * 64 + lane], b3v = P.b3[e];
    float h1a = fast_tanh(b1v + w10 * X0 + w11 * X1);
    float h1c = fast_tanh(b1v + w10 * X2 + w11 * X3);
    h1b[lane * 2]     = h1a;
    h1b[lane * 2 + 1] = h1c;
    __syncthreads();
    const float* h1g = h1b + (lane >> 2) * 8;
    float a2 = b2v;
    #pragma unroll
    for (int u = 0; u < 8; u++) a2 += P.w2[e * 512 + lane * 8 + u] * h1g[u];
    float h2v = fast_tanh(a2);
    float g3  = wsum(w3v * h2v);
    float Gn  = fast_tanh(b3v + g3);
    if (lane == 0) (ws + OFF_G)[row * 272 + s] = Gn;

    // gl/gr for step t+1 into the other parity buffer
    float hnext = (lane == 63) ? Gn : grow_G[(t + 1) + 4 * lane];
    __syncthreads();
    hb[lane] = hnext;
    __syncthreads();
    float glx = blv, grx = brv;
    #pragma unroll 4
    for (int f = 0; f < 64; f++) {
      float hv = hb[f];
      glx += hv * WlT[f * 64 + lane];
      grx += hv * WrT[f * 64 + lane];
    }
    (ws + OFF_GL + ((t + 1) & 1) * 131072)[row * 64 + lane] = glx;
    (ws + OFF_GR + ((t + 1) & 1) * 131072)[row * 64 + lane] = grx;
  }
}

extern "C" void kernel_launch(void* const* d_in, const int* in_sizes, int n_in,
                              void* d_out, int out_size, void* d_ws, size_t ws_size,
                              hipStream_t stream) {
  Params p;
  p.x     = (const float*)d_in[0];  p.noise = (const float*)d_in[1];
  p.aw    = (const float*)d_in[2];  p.ab    = (const float*)d_in[3];
  p.pe_w1 = (const float*)d_in[4];  p.pe_b1 = (const float*)d_in[5];
  p.bn_g  = (const float*)d_in[6];  p.bn_b  = (const float*)d_in[7];
  p.bn_m  = (const float*)d_in[8];  p.bn_v  = (const float*)d_in[9];
  p.pe_w2 = (const float*)d_in[10]; p.pe_b2 = (const float*)d_in[11];
  p.w1    = (const float*)d_in[12]; p.b1    = (const float*)d_in[13];
  p.w2    = (const float*)d_in[14]; p.b2    = (const float*)d_in[15];
  p.w3    = (const float*)d_in[16]; p.b3    = (const float*)d_in[17];
  p.wl    = (const float*)d_in[18]; p.bl    = (const float*)d_in[19];
  p.wr    = (const float*)d_in[20]; p.br    = (const float*)d_in[21];
  p.attn  = (const float*)d_in[22]; p.out_w = (const float*)d_in[23];
  p.out_b = (const float*)d_in[24]; p.ce_w  = (const float*)d_in[25];
  p.ce_b  = (const float*)d_in[26]; p.cd_w  = (const float*)d_in[27];
  p.cd_b  = (const float*)d_in[28]; p.q_w   = (const float*)d_in[29];
  p.q_b   = (const float*)d_in[30]; p.k_w   = (const float*)d_in[31];
  p.k_b   = (const float*)d_in[32];
  p.ws  = (float*)d_ws;
  p.out = (float*)d_out;

  k1_h0<<<dim3(512),  dim3(256), 0, stream>>>(p);
  k2_xf<<<dim3(2048), dim3(256), 0, stream>>>(p);
  k3_G <<<dim3(512),  dim3(256), 0, stream>>>(p);
  k4_qk<<<dim3(512),  dim3(256), 0, stream>>>(p);
  k5_adj<<<dim3(512), dim3(256), 0, stream>>>(p);
  for (int t = 0; t < 12; t++)
    k_step<<<dim3(512), dim3(256), 0, stream>>>(p, t);
}